// Round 10
// baseline (93.201 us; speedup 1.0000x reference)
//
#include <hip/hip_runtime.h>

// CurvatureLoss: pred (8,4,1024,1024) fp32 -> scalar loss. target unused.
// C=2 cols/lane scalar register-ring sweep, RCHUNK=16, rings {P:3, L:5, Rr:2},
// 20 steps fully unrolled. DPP (bound_ctrl=1) cross-lane. e0-norm softmax.
// Per-block result slots in ws (no atomics, no zeroing kernel) + one small
// finalize kernel. 2 launches total.

namespace {
constexpr int H = 1024, W = 1024, B = 8;
constexpr int VALID = 120;            // output cols per wave (64 lanes x 2 - 8)
constexpr int NSTRIPS = 9;            // 9 * 120 = 1080 >= 1024
constexpr int RCHUNK = 16;            // output rows per wave
constexpr int NCHUNKS = H / RCHUNK;   // 64
constexpr int WPB = 4;                // waves per block
constexpr int NTHREADS = 64 * WPB;
constexpr int NYG = NCHUNKS / WPB;    // 16 y-groups
constexpr int NBLOCKS = NSTRIPS * NYG * B;  // 1152
constexpr int SPG = NSTRIPS * NYG;    // 144 slots per (b) group
constexpr size_t HW = (size_t)H * W;
}

// DPP cross-lane: neighbor lane's value; OOB lanes read 0 (bound_ctrl=1, no
// old-value tie-off mov). Lanes 0/63 results are never consumed (epilogue gate).
__device__ __forceinline__ float dpp_left(float x) {   // lane n <- lane n-1
    return __builtin_bit_cast(float,
        __builtin_amdgcn_update_dpp(0, __builtin_bit_cast(int, x),
                                    0x138 /*wave_shr1*/, 0xf, 0xf, true));
}
__device__ __forceinline__ float dpp_right(float x) {  // lane n <- lane n+1
    return __builtin_bit_cast(float,
        __builtin_amdgcn_update_dpp(0, __builtin_bit_cast(int, x),
                                    0x130 /*wave_shl1*/, 0xf, 0xf, true));
}

template <bool RE>
__device__ __forceinline__ void load_row4(const float* __restrict__ basep, int row,
                                          float2 o[4]) {
    const int rc = RE ? min(max(row, 0), H - 1) : row;  // masked later
    const float* p = basep + (size_t)rc * W;
    o[0] = *(const float2*)p;
    o[1] = *(const float2*)(p + HW);
    o[2] = *(const float2*)(p + 2 * HW);
    o[3] = *(const float2*)(p + 3 * HW);
}

// e0-normalized softmax (ratios identical; inputs ~N(0,1), no overflow).
// Outputs {p1, p1+p2, p3}; masked to 0 where !ok (edge templates only).
template <bool EDGE>
__device__ __forceinline__ void softmax_col(float x0, float x1, float x2, float x3,
                                            bool ok, float& p1, float& p12,
                                            float& p3) {
    const float e1 = __expf(x1 - x0);
    const float e2 = __expf(x2 - x0);
    const float e3 = __expf(x3 - x0);
    const float t12 = e1 + e2;
    const float inv = __builtin_amdgcn_rcpf(1.f + (t12 + e3));
    if (EDGE) {
        p1  = ok ? e1 * inv : 0.f;
        p12 = ok ? t12 * inv : 0.f;
        p3  = ok ? e3 * inv : 0.f;
    } else {
        p1 = e1 * inv; p12 = t12 * inv; p3 = e3 * inv;
    }
}

__device__ __forceinline__ void acc_col(float gx, float gy, float gxp, float gxm,
                                        float gyp, float gym,
                                        float& s, unsigned int& c) {
    const float hxx = 2.f * gx - gxp - gxm;
    const float hxy = gxp - gxm;
    const float hyy = 2.f * gy - gyp - gym;
    const float ox = 1.f + gx, oy = 1.f + gy;
    const float numer = hxx * oy * oy - 2.f * hxy * gx * gy + hyy * ox * ox;
    const float xx = 1.f + gx * gx + gy * gy;
    const float xx3 = xx * xx * xx;
    const float rs = __builtin_amdgcn_rsqf(xx3);  // xx^-1.5
    const float c2 = numer * rs;                  // 2x true curvature
    const float ng = fmaxf(-c2, 0.f);
    s += ng;
    c += (ng != 0.f) ? 1u : 0u;
}

template <bool CE, bool RE>
__device__ __forceinline__ void sweep(const float* __restrict__ pred,
                                      int b, int strip, int chunk, int lane,
                                      float sacc0[3], float sacc1[3],
                                      unsigned int cacc0[3],
                                      unsigned int cacc1[3]) {
    const int r0 = chunk * RCHUNK;
    const int li0 = 2 * lane;            // local col index 0..127
    const int col0 = strip * VALID - 4 + li0;
    const int col1 = col0 + 1;
    const int colC = CE ? min(max(col0, 0), W - 2) : col0;  // even -> 8B aligned
    const float* basep = pred + (size_t)b * 4 * HW + colC;

    const bool cOK0 = !CE || ((unsigned)col0 < (unsigned)W);
    const bool cOK1 = !CE || ((unsigned)col1 < (unsigned)W);
    const float gxpM0 = (!CE || (col0 + 1 < W)) ? 1.f : 0.f;
    const float gxpM1 = (!CE || (col1 + 1 < W)) ? 1.f : 0.f;
    const float gxmM0 = (!CE || (col0 >= 1)) ? 1.f : 0.f;
    const float gxmM1 = (!CE || (col1 >= 1)) ? 1.f : 0.f;

    float P[3][3][2];    // prob ring [slot = i%3][field][col]
    float L[5][3][2];    // lap ring  [slot = i%5][field][col]
    float2 Rr[2][4];     // raw ring  [slot = i%2][channel], prefetch depth 2

    // Prologue: P[1] = prob(r0-3), P[2] = prob(r0-2);
    //           Rr[0] = raw(r0-1), Rr[1] = raw(r0).
    {
        float2 t[4];
        load_row4<RE>(basep, r0 - 3, t);
        const bool ok = !RE || ((unsigned)(r0 - 3) < (unsigned)H);
        softmax_col<CE || RE>(t[0].x, t[1].x, t[2].x, t[3].x, ok && cOK0,
                              P[1][0][0], P[1][1][0], P[1][2][0]);
        softmax_col<CE || RE>(t[0].y, t[1].y, t[2].y, t[3].y, ok && cOK1,
                              P[1][0][1], P[1][1][1], P[1][2][1]);
        load_row4<RE>(basep, r0 - 2, t);
        const bool ok2 = !RE || ((unsigned)(r0 - 2) < (unsigned)H);
        softmax_col<CE || RE>(t[0].x, t[1].x, t[2].x, t[3].x, ok2 && cOK0,
                              P[2][0][0], P[2][1][0], P[2][2][0]);
        softmax_col<CE || RE>(t[0].y, t[1].y, t[2].y, t[3].y, ok2 && cOK1,
                              P[2][0][1], P[2][1][1], P[2][2][1]);
    }
    load_row4<RE>(basep, r0 - 1, Rr[0]);
    load_row4<RE>(basep, r0 + 0, Rr[1]);

#pragma unroll
    for (int i = 0; i < RCHUNK + 4; ++i) {        // 20 steps, fully unrolled
        const int y = r0 - 4 + i;                  // output row of this step
        // 1) prob row y+3 from Rr[i%2] -> P[i%3]
        const bool pok = !RE || ((unsigned)(y + 3) < (unsigned)H);
        softmax_col<CE || RE>(Rr[i % 2][0].x, Rr[i % 2][1].x, Rr[i % 2][2].x,
                              Rr[i % 2][3].x, pok && cOK0,
                              P[i % 3][0][0], P[i % 3][1][0], P[i % 3][2][0]);
        softmax_col<CE || RE>(Rr[i % 2][0].y, Rr[i % 2][1].y, Rr[i % 2][2].y,
                              Rr[i % 2][3].y, pok && cOK1,
                              P[i % 3][0][1], P[i % 3][1][1], P[i % 3][2][1]);
        // 2) prefetch raw row y+5 -> Rr[i%2] (consumed at step i+2);
        //    last needed raw row is r0+18, loaded at i=17.
        if (i < RCHUNK + 2) load_row4<RE>(basep, y + 5, Rr[i % 2]);
        // 3) lap row y+2 -> L[i%5] from prob rows y+1, y+2, y+3
        const bool lok = !RE || ((unsigned)(y + 2) < (unsigned)H);
#pragma unroll
        for (int f = 0; f < 3; ++f) {
            const float topx = P[(i + 1) % 3][f][0], topy = P[(i + 1) % 3][f][1];
            const float midx = P[(i + 2) % 3][f][0], midy = P[(i + 2) % 3][f][1];
            const float botx = P[i % 3][f][0],       boty = P[i % 3][f][1];
            const float lft = dpp_left(midy);    // prob(li0-1)
            const float rgt = dpp_right(midx);   // prob(li0+2)
            float lx = (topx + botx) + (lft + midy) - 4.f * midx;
            float ly = (topy + boty) + (midx + rgt) - 4.f * midy;
            if (CE || RE) {
                lx = (lok && cOK0) ? lx : 0.f;
                ly = (lok && cOK1) ? ly : 0.f;
            }
            L[i % 5][f][0] = lx;
            L[i % 5][f][1] = ly;
        }
        // 4) output row y from lap rows y-2..y+2 (first 4 steps: warmup)
        if (i >= 4) {
            const float gypM = (!RE || (y + 1 < H)) ? 1.f : 0.f;
            const float gymM = (!RE || (y >= 1)) ? 1.f : 0.f;
#pragma unroll
            for (int f = 0; f < 3; ++f) {
                const float lcx = L[(i + 3) % 5][f][0];
                const float lcy = L[(i + 3) % 5][f][1];
                const float A  = dpp_left(lcy);   // lap(li0-1)
                const float Bm = dpp_left(lcx);   // lap(li0-2)
                const float Bp = dpp_right(lcx);  // lap(li0+2)
                const float Cc = dpp_right(lcy);  // lap(li0+3)
                const float gxx = lcy - A;
                const float gxy = Bp - lcx;
                float gxpx = gxy,       gxpy = Cc - lcy;   // gxp.x == gx.y
                float gxmx = lcx - Bm,  gxmy = gxx;        // gxm.y == gx.x
                if (CE) {
                    gxpx *= gxpM0; gxpy *= gxpM1;
                    gxmx *= gxmM0; gxmy *= gxmM1;
                }
                const float gyx = L[(i + 4) % 5][f][0] - L[(i + 2) % 5][f][0];
                const float gyy = L[(i + 4) % 5][f][1] - L[(i + 2) % 5][f][1];
                float gypx = L[i % 5][f][0] - lcx;
                float gypy = L[i % 5][f][1] - lcy;
                float gymx = lcx - L[(i + 1) % 5][f][0];
                float gymy = lcy - L[(i + 1) % 5][f][1];
                if (RE) {
                    gypx *= gypM; gypy *= gypM;
                    gymx *= gymM; gymy *= gymM;
                }
                acc_col(gxx, gyx, gxpx, gxmx, gypx, gymx, sacc0[f], cacc0[f]);
                acc_col(gxy, gyy, gxpy, gxmy, gypy, gymy, sacc1[f], cacc1[f]);
            }
        }
    }
}

__global__ __launch_bounds__(NTHREADS, 3)
void curvature_sweep(const float* __restrict__ pred,
                     float* __restrict__ S_ws,
                     unsigned int* __restrict__ C_ws) {
    __shared__ float redS[3][WPB];
    __shared__ unsigned int redC[3][WPB];

    const int strip = blockIdx.x;
    const int b = blockIdx.z;
    const int tid = threadIdx.x;
    const int wv = tid >> 6, lane = tid & 63;
    const int chunk = blockIdx.y * WPB + wv;

    const bool ce = (strip == 0) || (strip == NSTRIPS - 1);
    const bool re = (chunk == 0) || (chunk == NCHUNKS - 1);

    float sacc0[3] = {0.f, 0.f, 0.f}, sacc1[3] = {0.f, 0.f, 0.f};
    unsigned int cacc0[3] = {0u, 0u, 0u}, cacc1[3] = {0u, 0u, 0u};
    if (!ce && !re)
        sweep<false, false>(pred, b, strip, chunk, lane, sacc0, sacc1, cacc0, cacc1);
    else if (ce && !re)
        sweep<true, false>(pred, b, strip, chunk, lane, sacc0, sacc1, cacc0, cacc1);
    else if (!ce && re)
        sweep<false, true>(pred, b, strip, chunk, lane, sacc0, sacc1, cacc0, cacc1);
    else
        sweep<true, true>(pred, b, strip, chunk, lane, sacc0, sacc1, cacc0, cacc1);

    // Epilogue gate (hoisted): valid lanes 2..61 (local cols 4..123), col0<W.
    // col0 is even so col0<=1022 implies col1<=1023: one test covers both.
    const int col0 = strip * VALID - 4 + 2 * lane;
    const bool gOK = (lane >= 2) && (lane <= 61) && (col0 < W);

    // Wave reduction -> LDS -> per-block slot write (no atomics).
#pragma unroll
    for (int f = 0; f < 3; ++f) {
        float v = gOK ? 0.5f * (sacc0[f] + sacc1[f]) : 0.f;  // 0.5: denom fold
        unsigned int c = gOK ? (cacc0[f] + cacc1[f]) : 0u;
        for (int off = 32; off > 0; off >>= 1) {
            v += __shfl_xor(v, off, 64);
            c += __shfl_xor(c, off, 64);
        }
        if (lane == 0) { redS[f][wv] = v; redC[f][wv] = c; }
    }
    __syncthreads();
    if (tid < 3) {
        float v = 0.f;
        unsigned int c = 0;
        for (int w2 = 0; w2 < WPB; ++w2) { v += redS[tid][w2]; c += redC[tid][w2]; }
        const int bid = (b * NYG + blockIdx.y) * NSTRIPS + strip;
        S_ws[bid * 3 + tid] = v;
        C_ws[bid * 3 + tid] = c;
    }
}

// Reduce 1152 block-slots -> 24 (b,field) groups -> loss. Slots for batch b
// are the contiguous bid range [b*SPG, (b+1)*SPG).
__global__ __launch_bounds__(256)
void finalize_kernel(const float* __restrict__ S_ws,
                     const unsigned int* __restrict__ C_ws,
                     float* __restrict__ out) {
    __shared__ float ls[8][32];
    __shared__ unsigned int lcn[8][32];
    __shared__ float qv[32];
    const int t = threadIdx.x;
    const int g = t & 31;        // group id: b*3+f for g<24
    const int j = t >> 5;        // 0..7
    float s = 0.f;
    unsigned int c = 0;
    if (g < 24) {
        const int b = g / 3, f = g - 3 * b;
        const int base = b * SPG;
        for (int m = 0; m < SPG / 8; ++m) {       // 18 slots per thread
            const int k = base + j * (SPG / 8) + m;
            s += S_ws[k * 3 + f];
            c += C_ws[k * 3 + f];
        }
    }
    ls[j][g] = s;
    lcn[j][g] = c;
    __syncthreads();
    if (t < 32) {
        float ss = 0.f;
        unsigned int cc = 0;
        for (int r = 0; r < 8; ++r) { ss += ls[r][t]; cc += lcn[r][t]; }
        qv[t] = (cc > 0) ? ss / (float)cc : 0.f;  // max(c,1)==c when c>0
    }
    __syncthreads();
    if (t == 0) {
        float tot = 0.f;
        for (int g2 = 0; g2 < 24; ++g2) tot += qv[g2];
        out[0] = tot;
    }
}

extern "C" void kernel_launch(void* const* d_in, const int* in_sizes, int n_in,
                              void* d_out, int out_size, void* d_ws, size_t ws_size,
                              hipStream_t stream) {
    const float* pred = (const float*)d_in[0];
    float* S_ws = (float*)d_ws;
    unsigned int* C_ws = (unsigned int*)((char*)d_ws + NBLOCKS * 3 * sizeof(float));
    float* out = (float*)d_out;

    dim3 grid(NSTRIPS, NYG, B);
    hipLaunchKernelGGL(curvature_sweep, grid, dim3(NTHREADS), 0, stream,
                       pred, S_ws, C_ws);
    hipLaunchKernelGGL(finalize_kernel, dim3(1), dim3(256), 0, stream,
                       S_ws, C_ws, out);
}

// Round 11
// 56.655 us; speedup vs baseline: 1.6451x; 1.6451x over previous
//
#include <hip/hip_runtime.h>

// CurvatureLoss: pred (8,4,1024,1024) fp32 -> scalar loss. target unused.
// C=2 cols/lane register-ring sweep (v2f), RCHUNK=16, rings {P:4, L:5, Rr:4},
// 20 steps fully unrolled (R8-proven codegen shape). e0-norm softmax (6 exp),
// DPP bound_ctrl=1 cross-lane, per-block slot writes (no atomics), 2 launches.

namespace {
constexpr int H = 1024, W = 1024, B = 8;
constexpr int VALID = 120;            // output cols per wave (64 lanes x 2 - 8)
constexpr int NSTRIPS = 9;            // 9 * 120 = 1080 >= 1024
constexpr int RCHUNK = 16;            // output rows per wave
constexpr int NCHUNKS = H / RCHUNK;   // 64
constexpr int WPB = 2;                // waves per block (2304 blocks: 9/CU exact)
constexpr int NTHREADS = 64 * WPB;
constexpr int NYG = NCHUNKS / WPB;    // 32 y-groups
constexpr int NBLOCKS = NSTRIPS * NYG * B;  // 2304
constexpr int SPG = NSTRIPS * NYG;    // 288 slots per batch
constexpr size_t HW = (size_t)H * W;
}

using v2f = __attribute__((ext_vector_type(2))) float;

__device__ __forceinline__ v2f mk2(float a, float b) {
    v2f r; r.x = a; r.y = b; return r;
}

// DPP cross-lane: neighbor lane's value; OOB lanes read 0 (bound_ctrl=1 -> no
// old-value tie-off mov). Lane-0/63 results are never consumed (epilogue gate).
__device__ __forceinline__ float dpp_left(float x) {   // lane n <- lane n-1
    return __builtin_bit_cast(float,
        __builtin_amdgcn_update_dpp(0, __builtin_bit_cast(int, x),
                                    0x138 /*wave_shr1*/, 0xf, 0xf, true));
}
__device__ __forceinline__ float dpp_right(float x) {  // lane n <- lane n+1
    return __builtin_bit_cast(float,
        __builtin_amdgcn_update_dpp(0, __builtin_bit_cast(int, x),
                                    0x130 /*wave_shl1*/, 0xf, 0xf, true));
}

template <bool RE>
__device__ __forceinline__ void load_row4(const float* __restrict__ basep, int row,
                                          v2f o[4]) {
    const int rc = RE ? min(max(row, 0), H - 1) : row;  // masked later
    const float* p = basep + (size_t)rc * W;
    o[0] = *(const v2f*)p;
    o[1] = *(const v2f*)(p + HW);
    o[2] = *(const v2f*)(p + 2 * HW);
    o[3] = *(const v2f*)(p + 3 * HW);
}

// e0-normalized softmax over 4 channels, 2 columns (ratios identical to
// softmax; inputs ~N(0,1): exp args bounded, safe). p = {p1, p1+p2, p3}.
template <bool EDGE>
__device__ __forceinline__ void softmax_pair(const v2f x[4], bool ok0, bool ok1,
                                             v2f p[3]) {
    const float e1x = __expf(x[1].x - x[0].x), e1y = __expf(x[1].y - x[0].y);
    const float e2x = __expf(x[2].x - x[0].x), e2y = __expf(x[2].y - x[0].y);
    const float e3x = __expf(x[3].x - x[0].x), e3y = __expf(x[3].y - x[0].y);
    const float t12x = e1x + e2x, t12y = e1y + e2y;
    const float ix = __builtin_amdgcn_rcpf(1.f + (t12x + e3x));
    const float iy = __builtin_amdgcn_rcpf(1.f + (t12y + e3y));
    if (EDGE) {
        p[0] = mk2(ok0 ? e1x * ix : 0.f,   ok1 ? e1y * iy : 0.f);
        p[1] = mk2(ok0 ? t12x * ix : 0.f,  ok1 ? t12y * iy : 0.f);
        p[2] = mk2(ok0 ? e3x * ix : 0.f,   ok1 ? e3y * iy : 0.f);
    } else {
        p[0] = mk2(e1x * ix,   e1y * iy);
        p[1] = mk2(t12x * ix,  t12y * iy);
        p[2] = mk2(e3x * ix,   e3y * iy);
    }
}

template <bool CE, bool RE>
__device__ __forceinline__ void sweep(const float* __restrict__ pred,
                                      int b, int strip, int chunk, int lane,
                                      v2f sacc[3], unsigned int cacc0[3],
                                      unsigned int cacc1[3]) {
    const int r0 = chunk * RCHUNK;
    const int li0 = 2 * lane;            // local col index 0..127
    const int col0 = strip * VALID - 4 + li0;
    const int col1 = col0 + 1;
    const int colC = CE ? min(max(col0, 0), W - 2) : col0;  // even -> 8B aligned
    const float* basep = pred + (size_t)b * 4 * HW + colC;

    const bool cOK0 = !CE || ((unsigned)col0 < (unsigned)W);
    const bool cOK1 = !CE || ((unsigned)col1 < (unsigned)W);
    // gx +-1 shift pad masks (affect valid pixels' stencils; fold to 1 if !CE)
    const v2f gxpM = mk2((!CE || (col0 + 1 < W)) ? 1.f : 0.f,
                         (!CE || (col1 + 1 < W)) ? 1.f : 0.f);
    const v2f gxmM = mk2((!CE || (col0 >= 1)) ? 1.f : 0.f,
                         (!CE || (col1 >= 1)) ? 1.f : 0.f);

    v2f P[4][3];   // prob ring [slot = i%4][field]
    v2f L[5][3];   // lap ring  [slot = i%5][field]
    v2f Rr[4][4];  // raw ring  [slot = i%4][channel], prefetch depth 4 steps

    // Prologue: P[2] = prob(r0-3), P[3] = prob(r0-2);
    //           Rr[0..3] = raw rows r0-1 .. r0+2.
    {
        v2f t[4];
        load_row4<RE>(basep, r0 - 3, t);
        const bool ok = !RE || ((unsigned)(r0 - 3) < (unsigned)H);
        softmax_pair<CE || RE>(t, ok && cOK0, ok && cOK1, P[2]);
        load_row4<RE>(basep, r0 - 2, t);
        const bool ok2 = !RE || ((unsigned)(r0 - 2) < (unsigned)H);
        softmax_pair<CE || RE>(t, ok2 && cOK0, ok2 && cOK1, P[3]);
    }
    load_row4<RE>(basep, r0 - 1, Rr[0]);
    load_row4<RE>(basep, r0 + 0, Rr[1]);
    load_row4<RE>(basep, r0 + 1, Rr[2]);
    load_row4<RE>(basep, r0 + 2, Rr[3]);

#pragma unroll
    for (int i = 0; i < RCHUNK + 4; ++i) {        // 20 steps, fully unrolled
        const int y = r0 - 4 + i;                  // output row of this step
        // 1) prob row y+3 from Rr[i%4] -> P[i%4]
        const bool pok = !RE || ((unsigned)(y + 3) < (unsigned)H);
        softmax_pair<CE || RE>(Rr[i % 4], pok && cOK0, pok && cOK1, P[i % 4]);
        // 2) prefetch raw row y+7 -> Rr[i%4] (consumed at step i+4); last
        //    consumed raw row is r0+18, loaded at i=15 -> gate i<16.
        if (i < RCHUNK) load_row4<RE>(basep, y + 7, Rr[i % 4]);
        // 3) lap row y+2 -> L[i%5] from prob rows y+1, y+2, y+3
        const bool lok = !RE || ((unsigned)(y + 2) < (unsigned)H);
#pragma unroll
        for (int f = 0; f < 3; ++f) {
            const v2f top = P[(i + 2) % 4][f];
            const v2f mid = P[(i + 3) % 4][f];
            const v2f bot = P[i % 4][f];
            const float lft = dpp_left(mid.y);    // prob(li0-1)
            const float rgt = dpp_right(mid.x);   // prob(li0+2)
            const v2f horiz = mk2(lft, mid.x) + mk2(mid.y, rgt);
            v2f l = top + bot + horiz - 4.f * mid;
            if (CE || RE) {
                l = mk2((lok && cOK0) ? l.x : 0.f, (lok && cOK1) ? l.y : 0.f);
            }
            L[i % 5][f] = l;
        }
        // 4) output row y from lap rows y-2..y+2 (first 4 steps: warmup)
        if (i >= 4) {
            const float gypM = (!RE || (y + 1 < H)) ? 1.f : 0.f;
            const float gymM = (!RE || (y >= 1)) ? 1.f : 0.f;
#pragma unroll
            for (int f = 0; f < 3; ++f) {
                const v2f lm2 = L[(i + 1) % 5][f];
                const v2f lm1 = L[(i + 2) % 5][f];
                const v2f lc  = L[(i + 3) % 5][f];
                const v2f lp1 = L[(i + 4) % 5][f];
                const v2f lp2 = L[i % 5][f];
                const float A  = dpp_left(lc.y);   // lap(li0-1)
                const float Bm = dpp_left(lc.x);   // lap(li0-2)
                const float Bp = dpp_right(lc.x);  // lap(li0+2)
                const float Cc = dpp_right(lc.y);  // lap(li0+3)
                const v2f c   = lc;
                const v2f gx  = mk2(lc.y, Bp) - mk2(A, lc.x);
                const v2f gy  = lp1 - lm1;
                const v2f gxp = (mk2(Bp, Cc) - c) * gxpM;
                const v2f gxm = (c - mk2(Bm, A)) * gxmM;
                const v2f gyp = (lp2 - c) * gypM;
                const v2f gym = (c - lm2) * gymM;
                const v2f hxx = 2.f * gx - gxp - gxm;
                const v2f hxy = gxp - gxm;
                const v2f hyy = 2.f * gy - gyp - gym;
                const v2f ox = 1.f + gx, oy = 1.f + gy;
                const v2f numer = hxx * oy * oy - 2.f * hxy * (gx * gy)
                                + hyy * ox * ox;
                const v2f xx = 1.f + gx * gx + gy * gy;
                const v2f xx3 = xx * xx * xx;
                const float rs0 = __builtin_amdgcn_rsqf(xx3.x);  // xx^-1.5
                const float rs1 = __builtin_amdgcn_rsqf(xx3.y);
                // 2x true curvature; 0.5 folded into the epilogue.
                const float c2x = numer.x * rs0;
                const float c2y = numer.y * rs1;
                const float ngx = fmaxf(-c2x, 0.f);
                const float ngy = fmaxf(-c2y, 0.f);
                sacc[f].x += ngx;
                sacc[f].y += ngy;
                cacc0[f] += (ngx != 0.f) ? 1u : 0u;
                cacc1[f] += (ngy != 0.f) ? 1u : 0u;
            }
        }
    }
}

__global__ __launch_bounds__(NTHREADS, 4)
void curvature_sweep(const float* __restrict__ pred,
                     float* __restrict__ S_ws,
                     unsigned int* __restrict__ C_ws) {
    __shared__ float redS[3][WPB];
    __shared__ unsigned int redC[3][WPB];

    const int strip = blockIdx.x;
    const int b = blockIdx.z;
    const int tid = threadIdx.x;
    const int wv = tid >> 6, lane = tid & 63;
    const int chunk = blockIdx.y * WPB + wv;

    const bool ce = (strip == 0) || (strip == NSTRIPS - 1);
    const bool re = (chunk == 0) || (chunk == NCHUNKS - 1);

    v2f sacc[3] = {mk2(0.f, 0.f), mk2(0.f, 0.f), mk2(0.f, 0.f)};
    unsigned int cacc0[3] = {0u, 0u, 0u};
    unsigned int cacc1[3] = {0u, 0u, 0u};
    if (!ce && !re)
        sweep<false, false>(pred, b, strip, chunk, lane, sacc, cacc0, cacc1);
    else if (ce && !re)
        sweep<true, false>(pred, b, strip, chunk, lane, sacc, cacc0, cacc1);
    else if (!ce && re)
        sweep<false, true>(pred, b, strip, chunk, lane, sacc, cacc0, cacc1);
    else
        sweep<true, true>(pred, b, strip, chunk, lane, sacc, cacc0, cacc1);

    // Epilogue gate (hoisted): valid lanes 2..61 (local cols 4..123); col0
    // even, so col0 < W covers col1 too.
    const int col0 = strip * VALID - 4 + 2 * lane;
    const bool gOK = (lane >= 2) && (lane <= 61) && (col0 < W);

    // Wave reduction -> LDS -> per-block slot write (no atomics).
#pragma unroll
    for (int f = 0; f < 3; ++f) {
        float v = gOK ? 0.5f * (sacc[f].x + sacc[f].y) : 0.f;  // 0.5: denom fold
        unsigned int c = gOK ? (cacc0[f] + cacc1[f]) : 0u;
        for (int off = 32; off > 0; off >>= 1) {
            v += __shfl_xor(v, off, 64);
            c += __shfl_xor(c, off, 64);
        }
        if (lane == 0) { redS[f][wv] = v; redC[f][wv] = c; }
    }
    __syncthreads();
    if (tid < 3) {
        float v = 0.f;
        unsigned int c = 0;
        for (int w2 = 0; w2 < WPB; ++w2) { v += redS[tid][w2]; c += redC[tid][w2]; }
        const int bid = (b * NYG + blockIdx.y) * NSTRIPS + strip;
        S_ws[bid * 3 + tid] = v;
        C_ws[bid * 3 + tid] = c;
    }
}

// Reduce 2304 block-slots -> 24 (b,field) groups -> loss. Slots for batch b
// occupy the contiguous bid range [b*SPG, (b+1)*SPG).
__global__ __launch_bounds__(256)
void finalize_kernel(const float* __restrict__ S_ws,
                     const unsigned int* __restrict__ C_ws,
                     float* __restrict__ out) {
    __shared__ float ls[8][32];
    __shared__ unsigned int lcn[8][32];
    __shared__ float qv[32];
    const int t = threadIdx.x;
    const int g = t & 31;        // group id: b*3+f for g<24
    const int j = t >> 5;        // 0..7
    float s = 0.f;
    unsigned int c = 0;
    if (g < 24) {
        const int b = g / 3, f = g - 3 * b;
        const int base = b * SPG;
        for (int m = 0; m < SPG / 8; ++m) {       // 36 slots per thread
            const int k = base + j * (SPG / 8) + m;
            s += S_ws[k * 3 + f];
            c += C_ws[k * 3 + f];
        }
    }
    ls[j][g] = s;
    lcn[j][g] = c;
    __syncthreads();
    if (t < 32) {
        float ss = 0.f;
        unsigned int cc = 0;
        for (int r = 0; r < 8; ++r) { ss += ls[r][t]; cc += lcn[r][t]; }
        qv[t] = (cc > 0) ? ss / (float)cc : 0.f;  // max(c,1)==c when c>0
    }
    __syncthreads();
    if (t == 0) {
        float tot = 0.f;
        for (int g2 = 0; g2 < 24; ++g2) tot += qv[g2];
        out[0] = tot;
    }
}

extern "C" void kernel_launch(void* const* d_in, const int* in_sizes, int n_in,
                              void* d_out, int out_size, void* d_ws, size_t ws_size,
                              hipStream_t stream) {
    const float* pred = (const float*)d_in[0];
    float* S_ws = (float*)d_ws;
    unsigned int* C_ws = (unsigned int*)((char*)d_ws + NBLOCKS * 3 * sizeof(float));
    float* out = (float*)d_out;

    dim3 grid(NSTRIPS, NYG, B);
    hipLaunchKernelGGL(curvature_sweep, grid, dim3(NTHREADS), 0, stream,
                       pred, S_ws, C_ws);
    hipLaunchKernelGGL(finalize_kernel, dim3(1), dim3(256), 0, stream,
                       S_ws, C_ws, out);
}